// Round 3
// baseline (419.119 us; speedup 1.0000x reference)
//
#include <hip/hip_runtime.h>

typedef __attribute__((ext_vector_type(8))) short bf16x8;
typedef __attribute__((ext_vector_type(16))) float f32x16;

#define HH 8
#define DD 32
#define NB 512
#define BS 128
#define NIT 8     // buckets per block (pipelined)
#define LKB 40    // K row stride (elems): 32 + 8 pad
#define LVT 136   // Vt row stride (elems): 128 + 8 pad

// packed fp32x2 -> bf16x2, RNE (single instruction on gfx950)
__device__ __forceinline__ unsigned int cvtpk(float a, float b) {
    unsigned int r;
    asm("v_cvt_pk_bf16_f32 %0, %1, %2" : "=v"(r) : "v"(a), "v"(b));
    return r;
}

// issue global loads for bucket NN into prefetch regs (consumed by CONVERT)
#define LOADS(NN) do {                                                          \
    const int base_ = ((b * 65536 + (NN) * BS) * HH + h) * DD;                  \
    const float4* kv_ = (const float4*)(Kg + base_ + tok * (HH*DD) + half*16);  \
    rk0 = kv_[0]; rk1 = kv_[1]; rk2 = kv_[2]; rk3 = kv_[3];                     \
    const float* vb_ = Vg + base_ + (kg * 4) * (HH*DD) + dq * 4;                \
    rv0 = *(const float4*)(vb_);            rv1 = *(const float4*)(vb_ + HH*DD);\
    rv2 = *(const float4*)(vb_ + 2*HH*DD);  rv3 = *(const float4*)(vb_ + 3*HH*DD);\
    const float* qr_ = Qg + base_ + (q0row + l31) * (HH*DD) + hi * 8;           \
    ra0 = *(const float4*)(qr_);      ra1 = *(const float4*)(qr_ + 4);          \
    ra2 = *(const float4*)(qr_ + 16); ra3 = *(const float4*)(qr_ + 20);         \
} while (0)

// fp32 prefetch regs -> bf16 LDS buffer BUF (+ Q fragments in regs)
#define CONVERT(BUF) do {                                                       \
    uint4* kd_ = (uint4*)(&Kb[BUF][tok * LKB + half * 16]);                     \
    kd_[0] = make_uint4(cvtpk(rk0.x, rk0.y), cvtpk(rk0.z, rk0.w),               \
                        cvtpk(rk1.x, rk1.y), cvtpk(rk1.z, rk1.w));              \
    kd_[1] = make_uint4(cvtpk(rk2.x, rk2.y), cvtpk(rk2.z, rk2.w),               \
                        cvtpk(rk3.x, rk3.y), cvtpk(rk3.z, rk3.w));              \
    unsigned short* vt_ = &Vt[BUF][0];                                          \
    *(uint2*)(vt_ + (dq*4+0)*LVT + kgp*4) = make_uint2(cvtpk(rv0.x, rv1.x), cvtpk(rv2.x, rv3.x)); \
    *(uint2*)(vt_ + (dq*4+1)*LVT + kgp*4) = make_uint2(cvtpk(rv0.y, rv1.y), cvtpk(rv2.y, rv3.y)); \
    *(uint2*)(vt_ + (dq*4+2)*LVT + kgp*4) = make_uint2(cvtpk(rv0.z, rv1.z), cvtpk(rv2.z, rv3.z)); \
    *(uint2*)(vt_ + (dq*4+3)*LVT + kgp*4) = make_uint2(cvtpk(rv0.w, rv1.w), cvtpk(rv2.w, rv3.w)); \
    qf0 = __builtin_bit_cast(bf16x8, make_uint4(                                \
          cvtpk(ra0.x*cs, ra0.y*cs), cvtpk(ra0.z*cs, ra0.w*cs),                 \
          cvtpk(ra1.x*cs, ra1.y*cs), cvtpk(ra1.z*cs, ra1.w*cs)));               \
    qf1 = __builtin_bit_cast(bf16x8, make_uint4(                                \
          cvtpk(ra2.x*cs, ra2.y*cs), cvtpk(ra2.z*cs, ra2.w*cs),                 \
          cvtpk(ra3.x*cs, ra3.y*cs), cvtpk(ra3.z*cs, ra3.w*cs)));               \
} while (0)

__global__ __launch_bounds__(256, 3) void battn_kernel(
    const float* __restrict__ Qg, const float* __restrict__ Kg,
    const float* __restrict__ Vg, const int* __restrict__ SB,
    float* __restrict__ Og)
{
    __shared__ unsigned short Kb[2][BS * LKB];   // K bf16 [key][d], double-buffered
    __shared__ unsigned short Vt[2][DD * LVT];   // V bf16 [d][sigma(key)], double-buffered

    const int bid = blockIdx.x;
    const int h = bid & 7;
    const int g = bid >> 3;
    const int b = g >> 6;
    const int n0 = (g & 63) * NIT;
    const int tid = threadIdx.x;

    const int lane = tid & 63;
    const int w = tid >> 6;        // wave id: owns queries [w*32, w*32+32)
    const int l31 = lane & 31;
    const int hi = lane >> 5;
    const int q0row = w * 32;

    // static staging coordinates
    const int tok = tid >> 1, half = tid & 1;   // K: thread -> (token, 16-float half)
    const int kg = tid >> 3, dq = tid & 7;      // V: thread -> (4-key group, 4-d quad)
    // sigma: swap key bits 2,3 == swap kg bits 0,1
    const int kgp = (kg & ~3) | ((kg & 1) << 1) | ((kg >> 1) & 1);

    const float cs = 0.17677669529663687f * 1.4426950408889634f; // 1/sqrt(D) * log2(e)

    float4 rk0, rk1, rk2, rk3, rv0, rv1, rv2, rv3, ra0, ra1, ra2, ra3;
    bf16x8 qf0, qf1;
    int st, en;

    // ---- prologue: bucket n0 (cold) ----
    LOADS(n0);
    {
        const int sb = (b * NB + n0) * 2;
        st = SB[sb]; en = SB[sb + 1];
    }
    CONVERT(0);
    __syncthreads();

    const f32x16 z = {0.f,0.f,0.f,0.f, 0.f,0.f,0.f,0.f, 0.f,0.f,0.f,0.f, 0.f,0.f,0.f,0.f};

    int cur = 0;
    #pragma unroll 1
    for (int it = 0; it < NIT; ++it) {
        const int n = n0 + it;
        const int kbase = n * BS;
        const int baseO = ((b * 65536 + n * BS) * HH + h) * DD;
        const bool full = (st <= kbase) && (en >= kbase + BS);
        const bool pf = (it + 1 < NIT);

        // 1. issue next bucket's global loads (in flight during compute)
        int stn = 0, enn = 0;
        if (pf) {
            LOADS(n + 1);
            const int sbn = (b * NB + n + 1) * 2;
            stn = SB[sbn]; enn = SB[sbn + 1];
        }

        // 2. flash compute on LDS[cur]: online softmax over four 32-key tiles.
        // S^T: A=K(M=key), B=Q(N=query); C layout col(query)=l31,
        // row(key in tile)=(r&3)+8*(r>>2)+4*hi. sigma-permuted V makes the PV
        // A-operand exactly the lane's own P values in register order.
        f32x16 o = z;
        float m = -30.0f, l = 0.f;
        #pragma unroll
        for (int kt = 0; kt < 4; ++kt) {
            const unsigned short* kp = &Kb[cur][(kt * 32 + l31) * LKB + hi * 8];
            bf16x8 kf0 = *(const bf16x8*)(kp);
            bf16x8 kf1 = *(const bf16x8*)(kp + 16);
            f32x16 s = __builtin_amdgcn_mfma_f32_32x32x16_bf16(kf0, qf0, z, 0, 0, 0);
            s = __builtin_amdgcn_mfma_f32_32x32x16_bf16(kf1, qf1, s, 0, 0, 0);

            if (!full) {   // block-uniform branch
                #pragma unroll
                for (int r = 0; r < 16; ++r) {
                    const int ap = kbase + kt * 32 + ((r & 3) + 8 * (r >> 2) + 4 * hi);
                    s[r] = ((ap >= st) && (ap < en)) ? s[r] : -1.0e30f;
                }
            }

            float tmax = s[0];
            #pragma unroll
            for (int r = 1; r < 16; ++r) tmax = fmaxf(tmax, s[r]);
            tmax = fmaxf(tmax, __shfl_xor(tmax, 32));

            if (kt == 0) {
                m = fmaxf(tmax, -30.0f);
            } else if (__any(tmax > m + 8.0f)) {   // deferred rescale (THR=8)
                const float nm = fmaxf(m, tmax);
                const float sc = exp2f(m - nm);
                #pragma unroll
                for (int r = 0; r < 16; ++r) o[r] *= sc;
                l *= sc;
                m = nm;
            }

            #pragma unroll
            for (int j = 0; j < 2; ++j) {
                const int rb = 8 * j;
                float p0 = exp2f(s[rb + 0] - m);
                float p1 = exp2f(s[rb + 1] - m);
                float p2 = exp2f(s[rb + 2] - m);
                float p3 = exp2f(s[rb + 3] - m);
                float p4 = exp2f(s[rb + 4] - m);
                float p5 = exp2f(s[rb + 5] - m);
                float p6 = exp2f(s[rb + 6] - m);
                float p7 = exp2f(s[rb + 7] - m);
                l += ((p0 + p1) + (p2 + p3)) + ((p4 + p5) + (p6 + p7));
                bf16x8 pa = __builtin_bit_cast(bf16x8, make_uint4(
                    cvtpk(p0, p1), cvtpk(p2, p3), cvtpk(p4, p5), cvtpk(p6, p7)));
                bf16x8 vf = *(const bf16x8*)(&Vt[cur][l31 * LVT + (kt * 2 + j) * 16 + hi * 8]);
                o = __builtin_amdgcn_mfma_f32_32x32x16_bf16(pa, vf, o, 0, 0, 0);
            }
        }
        l += __shfl_xor(l, 32);
        const float inv = 1.0f / l;   // lane holds denom for query q0row+l31

        // 3. prefetched fp32 -> bf16 LDS[cur^1] (loads landed during compute);
        //    overwrites qf for next iteration (current compute done).
        if (pf) CONVERT(cur ^ 1);

        // 4. epilogue: normalize, gate invalid queries, store fp32
        #pragma unroll
        for (int r = 0; r < 16; ++r) {
            const int row = (r & 3) + 8 * (r >> 2) + 4 * hi;
            const int q = q0row + row;
            float iv = __shfl(inv, row);
            if (!full) {
                const int ap = kbase + q;
                iv = ((ap >= st) && (ap < en)) ? iv : 0.f;
            }
            Og[baseO + q * (HH * DD) + l31] = o[r] * iv;
        }

        st = stn; en = enn;
        __syncthreads();
        cur ^= 1;
    }
}

extern "C" void kernel_launch(void* const* d_in, const int* in_sizes, int n_in,
                              void* d_out, int out_size, void* d_ws, size_t ws_size,
                              hipStream_t stream) {
    const float* Q = (const float*)d_in[0];
    const float* K = (const float*)d_in[1];
    const float* V = (const float*)d_in[2];
    const int* SB  = (const int*)d_in[3];
    float* O = (float*)d_out;
    battn_kernel<<<dim3(8192 / NIT), dim3(256), 0, stream>>>(Q, K, V, SB, O);
}